// Round 4
// baseline (446.793 us; speedup 1.0000x reference)
//
#include <hip/hip_runtime.h>
#include <hip/hip_bf16.h>
#include <math.h>

#define TEMP 0.0005f

typedef __attribute__((ext_vector_type(8))) short short8v;
typedef __attribute__((ext_vector_type(4))) float float4v;

__device__ inline short bf16bits(float v) {
    union { float f; unsigned u; } x; x.f = v;
    unsigned r = x.u + 0x7FFFu + ((x.u >> 16) & 1u);   // RNE
    return (short)(r >> 16);
}

// ---------- weight fp32 -> bf16 (all 5 tensors, one pass) ----------
#define NW0 1572864   // wk1: 1024*512*3
#define NW1 1654784   // +wk2: 80*1024
#define NW2 1693184   // +wq1: 160*80*3
#define NW3 1705984   // +wq2: 80*160
#define NW4 1712384   // +wq3: 80*80
__global__ __launch_bounds__(256)
void cvtw_kernel(const float* __restrict__ w0, const float* __restrict__ w1,
                 const float* __restrict__ w2, const float* __restrict__ w3,
                 const float* __restrict__ w4, short* __restrict__ dst)
{
    int i = blockIdx.x * 256 + threadIdx.x;
    if (i >= NW4) return;
    float v;
    if      (i < NW0) v = w0[i];
    else if (i < NW1) v = w1[i - NW0];
    else if (i < NW2) v = w2[i - NW1];
    else if (i < NW3) v = w3[i - NW2];
    else              v = w4[i - NW3];
    dst[i] = bf16bits(v);
}

// ---------- unified conv-as-GEMM via bf16 MFMA ----------
// y[b][co][t] = relu?( bias[co] + sum_{ci,r} w[co][ci*KSZ+r] * x[b][ci][t+r-PAD] )
// GEMM: A = w (M x K, K=Cin*KSZ, bf16), B = im2col(x) (K x T), per batch.
// Block tile: BM=128 x BN=64, BK=64. 4 waves (2x2), wave tile 64x32 (4x2 frags).
template<int KSZ, int PAD, bool RELU>
__global__ __launch_bounds__(256)
void convmm_kernel(const float* __restrict__ x, const short* __restrict__ w,
                   const float* __restrict__ bias, float* __restrict__ y,
                   int Cin, int M, int T)
{
    constexpr int BM = 128, BN = 64, BK = 64, BKP = BK + 8;  // +8 bf16 pad: 2-way banks only
    const int K   = Cin * KSZ;
    const int b   = blockIdx.x;
    const int m0  = blockIdx.y * BM;
    const int t0  = blockIdx.z * BN;
    const int tid = threadIdx.x;
    const int lane = tid & 63;
    const int wid  = tid >> 6;
    const int wm   = wid >> 1;      // 0..1
    const int wn   = wid & 1;       // 0..1
    const int l15  = lane & 15;
    const int lg   = lane >> 4;     // 0..3

    __shared__ short As[BM][BKP];
    __shared__ short Bs[BN][BKP];

    float4v acc[4][2];
#pragma unroll
    for (int mi = 0; mi < 4; ++mi)
#pragma unroll
        for (int ni = 0; ni < 2; ++ni)
            acc[mi][ni] = float4v{0.f, 0.f, 0.f, 0.f};

    const float* xb = x + (size_t)b * Cin * T;

    const int arow = tid >> 1;            // 0..127
    const int acol = (tid & 1) * 32;      // {0,32}
    const int brow = tid >> 2;            // 0..63
    const int bcol = (tid & 3) * 16;      // {0,16,32,48}
    const int bt   = t0 + brow;           // output position for B staging row

    for (int kk = 0; kk < K; kk += BK) {
        // ---- stage A (weights, bf16, contiguous) : 4 x 8-element vector loads
#pragma unroll
        for (int i = 0; i < 4; ++i) {
            int kcol = acol + i * 8;
            int gk = kk + kcol;
            short8v v;
            if ((m0 + arow) < M && (gk + 7) < K) {
                v = *(const short8v*)&w[(size_t)(m0 + arow) * K + gk];
            } else if ((m0 + arow) < M) {
#pragma unroll
                for (int e = 0; e < 8; ++e)
                    v[e] = (gk + e < K) ? w[(size_t)(m0 + arow) * K + gk + e] : (short)0;
            } else {
#pragma unroll
                for (int e = 0; e < 8; ++e) v[e] = 0;
            }
            *(short8v*)&As[arow][kcol] = v;
        }
        // ---- stage B (im2col of x, fp32 -> bf16) : 16 scalar loads
#pragma unroll
        for (int g = 0; g < 2; ++g) {
            short8v v;
#pragma unroll
            for (int e = 0; e < 8; ++e) {
                int kl = bcol + g * 8 + e;
                int k  = kk + kl;
                short val = 0;
                if (k < K && bt < T) {
                    int ci = k / KSZ;           // const divisor (1 or 3)
                    int r  = k - ci * KSZ;
                    int ts = bt + r - PAD;
                    if (ts >= 0 && ts < T)
                        val = bf16bits(xb[(size_t)ci * T + ts]);
                }
                v[e] = val;
            }
            *(short8v*)&Bs[brow][bcol + g * 8] = v;
        }
        __syncthreads();

        // ---- MFMA: two k32 sub-steps
#pragma unroll
        for (int ks = 0; ks < 2; ++ks) {
            short8v a[4], bb[2];
#pragma unroll
            for (int mi = 0; mi < 4; ++mi)
                a[mi] = *(const short8v*)&As[wm * 64 + mi * 16 + l15][ks * 32 + lg * 8];
#pragma unroll
            for (int ni = 0; ni < 2; ++ni)
                bb[ni] = *(const short8v*)&Bs[wn * 32 + ni * 16 + l15][ks * 32 + lg * 8];
#pragma unroll
            for (int mi = 0; mi < 4; ++mi)
#pragma unroll
                for (int ni = 0; ni < 2; ++ni)
                    acc[mi][ni] = __builtin_amdgcn_mfma_f32_16x16x32_bf16(
                        a[mi], bb[ni], acc[mi][ni], 0, 0, 0);
        }
        __syncthreads();
    }

    // ---- epilogue: C[row=(lane>>4)*4+j][col=lane&15] (m89-verified layout)
#pragma unroll
    for (int mi = 0; mi < 4; ++mi) {
#pragma unroll
        for (int ni = 0; ni < 2; ++ni) {
#pragma unroll
            for (int j = 0; j < 4; ++j) {
                int co = m0 + wm * 64 + mi * 16 + lg * 4 + j;
                int t  = t0 + wn * 32 + ni * 16 + l15;
                if (co < M && t < T) {
                    float v = acc[mi][ni][j] + bias[co];
                    if (RELU) v = fmaxf(v, 0.f);
                    y[((size_t)b * M + co) * T + t] = v;
                }
            }
        }
    }
}

// ---------- fused L2-dist attention + log_softmax + log-prior + softmax ----------
__global__ __launch_bounds__(256)
void attn_kernel(const float* __restrict__ qenc, const float* __restrict__ kenc,
                 const float* __restrict__ prior, float* __restrict__ out_attn,
                 float* __restrict__ out_lp)
{
    constexpr int Ca = 80, Ten = 160, Tde = 800, IT = 32, CP = 84;
    __shared__ float ke[Ten][CP];
    __shared__ float qe[IT][CP];
    const int b   = blockIdx.x;
    const int i0  = blockIdx.y * IT;
    const int tid = threadIdx.x;

    for (int l = tid; l < Ca * Ten; l += 256) {
        int c = l / Ten, j = l - c * Ten;
        ke[j][c] = kenc[((size_t)b * Ca + c) * Ten + j];
    }
    for (int l = tid; l < Ca * IT; l += 256) {
        int c = l / IT, ii = l - c * IT;
        qe[ii][c] = qenc[((size_t)b * Ca + c) * Tde + (i0 + ii)];
    }
    __syncthreads();

    const int ii = tid >> 3;
    const int jl = tid & 7;
    const int i  = i0 + ii;

    float s[20];
#pragma unroll
    for (int jj = 0; jj < 20; ++jj) {
        int j = jl + jj * 8;
        float a0 = 0.f, a1 = 0.f, a2 = 0.f, a3 = 0.f;
#pragma unroll
        for (int c = 0; c < Ca; c += 4) {
            float4 qv = *(const float4*)&qe[ii][c];
            float4 kv = *(const float4*)&ke[j][c];
            float d0 = qv.x - kv.x, d1 = qv.y - kv.y;
            float d2 = qv.z - kv.z, d3 = qv.w - kv.w;
            a0 += d0 * d0; a1 += d1 * d1; a2 += d2 * d2; a3 += d3 * d3;
        }
        s[jj] = -TEMP * ((a0 + a1) + (a2 + a3));
    }

    float m = -INFINITY;
#pragma unroll
    for (int jj = 0; jj < 20; ++jj) m = fmaxf(m, s[jj]);
#pragma unroll
    for (int d = 1; d < 8; d <<= 1) m = fmaxf(m, __shfl_xor(m, d));
    float sum = 0.f;
#pragma unroll
    for (int jj = 0; jj < 20; ++jj) sum += expf(s[jj] - m);
#pragma unroll
    for (int d = 1; d < 8; d <<= 1) sum += __shfl_xor(sum, d);
    float lse = logf(sum) + m;

    float lp[20];
    const float* prow = prior + ((size_t)b * Tde + i) * Ten;
#pragma unroll
    for (int jj = 0; jj < 20; ++jj) {
        int j = jl + jj * 8;
        lp[jj] = (s[jj] - lse) + logf(prow[j] + 1e-8f);
    }

    float m2 = -INFINITY;
#pragma unroll
    for (int jj = 0; jj < 20; ++jj) m2 = fmaxf(m2, lp[jj]);
#pragma unroll
    for (int d = 1; d < 8; d <<= 1) m2 = fmaxf(m2, __shfl_xor(m2, d));
    float e[20]; float s2 = 0.f;
#pragma unroll
    for (int jj = 0; jj < 20; ++jj) { e[jj] = expf(lp[jj] - m2); s2 += e[jj]; }
#pragma unroll
    for (int d = 1; d < 8; d <<= 1) s2 += __shfl_xor(s2, d);
    float inv = 1.f / s2;

    float* o0 = out_attn + ((size_t)b * Tde + i) * Ten;
    float* o1 = out_lp   + ((size_t)b * Tde + i) * Ten;
#pragma unroll
    for (int jj = 0; jj < 20; ++jj) {
        int j = jl + jj * 8;
        o0[j] = e[jj] * inv;
        o1[j] = lp[jj];
    }
}

extern "C" void kernel_launch(void* const* d_in, const int* in_sizes, int n_in,
                              void* d_out, int out_size, void* d_ws, size_t ws_size,
                              hipStream_t stream)
{
    const float* queries = (const float*)d_in[0];   // (4,80,800)
    const float* keys    = (const float*)d_in[1];   // (4,512,160)
    const float* prior   = (const float*)d_in[3];   // (4,800,160)
    const float* wk1 = (const float*)d_in[4];
    const float* bk1 = (const float*)d_in[5];
    const float* wk2 = (const float*)d_in[6];
    const float* bk2 = (const float*)d_in[7];
    const float* wq1 = (const float*)d_in[8];
    const float* bq1 = (const float*)d_in[9];
    const float* wq2 = (const float*)d_in[10];
    const float* bq2 = (const float*)d_in[11];
    const float* wq3 = (const float*)d_in[12];
    const float* bq3 = (const float*)d_in[13];

    // workspace layout (floats)
    float* wsp  = (float*)d_ws;
    short* wbf  = (short*)wsp;          // 1712384 bf16 = 856192 float slots
    float* k1   = wsp + 856192;         // 4*1024*160 = 655360
    float* q1   = k1 + 655360;          // 4*160*800  = 512000
    float* q2   = q1 + 512000;          // 4*80*800   = 256000
    float* kenc = q2 + 256000;          // 4*80*160   = 51200
    float* qenc = kenc + 51200;         // 4*80*800   = 256000

    const short* wb_k1 = wbf;
    const short* wb_k2 = wbf + NW0;
    const short* wb_q1 = wbf + NW1;
    const short* wb_q2 = wbf + NW2;
    const short* wb_q3 = wbf + NW3;

    float* out0 = (float*)d_out;          // attn (4,1,800,160)
    float* out1 = out0 + 4 * 800 * 160;   // attn_logprob

    // 0) weights -> bf16
    hipLaunchKernelGGL(cvtw_kernel, dim3((NW4 + 255) / 256), dim3(256), 0, stream,
                       wk1, wk2, wq1, wq2, wq3, wbf);

    // keys path: conv3(512->1024)+relu ; conv1(1024->80)
    hipLaunchKernelGGL((convmm_kernel<3, 1, true>), dim3(4, 8, 3), dim3(256), 0, stream,
                       keys, wb_k1, bk1, k1, 512, 1024, 160);
    hipLaunchKernelGGL((convmm_kernel<1, 0, false>), dim3(4, 1, 3), dim3(256), 0, stream,
                       k1, wb_k2, bk2, kenc, 1024, 80, 160);

    // queries path: conv3(80->160)+relu ; conv1(160->80)+relu ; conv1(80->80)
    hipLaunchKernelGGL((convmm_kernel<3, 1, true>), dim3(4, 2, 13), dim3(256), 0, stream,
                       queries, wb_q1, bq1, q1, 80, 160, 800);
    hipLaunchKernelGGL((convmm_kernel<1, 0, true>), dim3(4, 1, 13), dim3(256), 0, stream,
                       q1, wb_q2, bq2, q2, 160, 80, 800);
    hipLaunchKernelGGL((convmm_kernel<1, 0, false>), dim3(4, 1, 13), dim3(256), 0, stream,
                       q2, wb_q3, bq3, qenc, 80, 80, 800);

    // fused attention
    hipLaunchKernelGGL(attn_kernel, dim3(4, 25), dim3(256), 0, stream,
                       qenc, kenc, prior, out0, out1);
}

// Round 9
// 200.489 us; speedup vs baseline: 2.2285x; 2.2285x over previous
//
#include <hip/hip_runtime.h>
#include <hip/hip_bf16.h>
#include <math.h>

#define TEMP 0.0005f

typedef __attribute__((ext_vector_type(8))) short short8v;
typedef __attribute__((ext_vector_type(4))) float float4v;

__device__ inline short bf16bits(float v) {
    union { float f; unsigned u; } x; x.f = v;
    unsigned r = x.u + 0x7FFFu + ((x.u >> 16) & 1u);   // RNE
    return (short)(r >> 16);
}

// ============ workspace layout (short-element offsets from wbf) ============
// Total footprint 9.59 MB. Overlaps rely on stream ordering:
//   q1T aliases ikeys (ikeys dead after keys-conv3 completes)
//   q2T aliases k1T   (k1T dead after keys-conv1 completes)
#define WB_K1   0          // 1024 x 1536
#define WB_K2   1572864    // 80 x 1024
#define WB_Q1   1654784    // 160 x 256 (K=240 -> 256)
#define WB_Q2   1695744    // 80 x 192  (K=160 -> 192)
#define WB_Q3   1711104    // 80 x 128  (K=80  -> 128)
#define WB_END  1721344
#define O_IKEYS 1721344    // 4*160*1536 = 983040 bf16 im2colT(keys)
#define O_IQ    2704384    // 4*800*256  = 819200 bf16 im2colT(queries)
#define O_K1T   3523584    // 4*160*1024 = 655360 bf16
#define O_Q1T   O_IKEYS    // 4*800*192  = 614400 bf16 (alias, fits in 983040)
#define O_Q2T   O_K1T      // 4*800*128  = 409600 bf16 (alias, fits in 655360)
#define SH_END  4178944
// fp32 (float offsets from wsp)
#define OF_KENC (SH_END/2)          // 4*160*80 f32 = 51200
#define OF_QENC (OF_KENC + 51200)   // 4*800*80 f32 = 256000  -> end 2396672 floats

// ---------- weights fp32 -> bf16 with K zero-padding ----------
// NOTE (R7 fix): wq3 is (80,80): source K = 80 (NOT 128). Reading it with
// Ks=128 was a 15KB OOB read -> the R5/R7 core dumps.
__global__ __launch_bounds__(256)
void cvtw_kernel(const float* __restrict__ w0, const float* __restrict__ w1,
                 const float* __restrict__ w2, const float* __restrict__ w3,
                 const float* __restrict__ w4, short* __restrict__ dst)
{
    int i = blockIdx.x * 256 + threadIdx.x;
    if (i >= WB_END) return;
    const float* src; int rem, Ks, Kd;
    if      (i < WB_K2) { src = w0; rem = i;         Ks = 1536; Kd = 1536; }
    else if (i < WB_Q1) { src = w1; rem = i - WB_K2; Ks = 1024; Kd = 1024; }
    else if (i < WB_Q2) { src = w2; rem = i - WB_Q1; Ks = 240;  Kd = 256;  }
    else if (i < WB_Q3) { src = w3; rem = i - WB_Q2; Ks = 160;  Kd = 192;  }
    else                { src = w4; rem = i - WB_Q3; Ks = 80;   Kd = 128;  }
    int row = rem / Kd, col = rem - row * Kd;
    dst[i] = (col < Ks) ? bf16bits(src[row * Ks + col]) : (short)0;
}

// ---------- im2colT builder: out[b][t][ci*3+r] = bf16(x[b][ci][t+r-1]) ----------
__global__ __launch_bounds__(256)
void im2col_kernel(const float* __restrict__ keys, const float* __restrict__ queries,
                   short* __restrict__ ikeys, short* __restrict__ iq)
{
    int bid = blockIdx.x, tid = threadIdx.x;
    if (bid < 3840) {
        int row = bid / 6, chunk = bid - 6 * (bid / 6);
        int b = row / 160, t = row - b * 160;
        int k = chunk * 256 + tid;          // < 1536 always
        int c = k / 3, r = k - 3 * c;
        int ts = t + r - 1;
        float v = (ts >= 0 && ts < 160) ? keys[((size_t)b * 512 + c) * 160 + ts] : 0.f;
        ikeys[(size_t)row * 1536 + k] = bf16bits(v);
    } else {
        int row = bid - 3840;
        int b = row / 800, t = row - b * 800;
        int k = tid;
        short out = 0;
        if (k < 240) {
            int c = k / 3, r = k - 3 * c;
            int ts = t + r - 1;
            if (ts >= 0 && ts < 800)
                out = bf16bits(queries[((size_t)b * 80 + c) * 800 + ts]);
        }
        iq[(size_t)row * 256 + k] = out;
    }
}

// ---------- conv-as-GEMM, bf16 MFMA, k-contiguous B source ----------
// A: [M][Kp] bf16 weights. B: [b][T][Kp] bf16. Block 128x64xBK64, 4 waves 2x2.
// OUTF32=false: out bf16 [b][T][Mpad] (co in [M,Mpad) zero-filled = next layer K-pad)
// OUTF32=true : out f32  [b][T][M]
template<bool RELU, bool OUTF32>
__global__ __launch_bounds__(256)
void convmm_kernel(const short* __restrict__ Bsrc, const short* __restrict__ A,
                   const float* __restrict__ bias, void* __restrict__ outv,
                   int Kp, int M, int Mpad, int T)
{
    constexpr int BKP = 72;   // 64 + 8 pad
    const int b   = blockIdx.x;
    const int m0  = blockIdx.y * 128;
    const int t0  = blockIdx.z * 64;
    const int tid = threadIdx.x;
    const int lane = tid & 63;
    const int wid  = tid >> 6;
    const int wm   = wid >> 1, wn = wid & 1;
    const int l15  = lane & 15, lg = lane >> 4;

    __shared__ short As[128][BKP];
    __shared__ short Bs[64][BKP];

    float4v acc[4][2];
#pragma unroll
    for (int mi = 0; mi < 4; ++mi)
#pragma unroll
        for (int ni = 0; ni < 2; ++ni) acc[mi][ni] = float4v{0.f,0.f,0.f,0.f};

    const int r4  = tid >> 2;          // 0..63
    const int c8  = (tid & 3) * 8;     // 0..24
    const int bt  = t0 + r4;
    const short8v zz = {0,0,0,0,0,0,0,0};
    const size_t browbase = ((size_t)b * T + bt) * Kp;

    short8v ar[4], br[2], arn[4], brn[2];
    const int nk = Kp >> 6;

#define LOAD_AB(AR, BR, KKV) do { int _kk = (KKV);                                   \
    _Pragma("unroll")                                                                 \
    for (int u = 0; u < 4; ++u) {                                                     \
        int row = m0 + r4 + (u >> 1) * 64;                                            \
        AR[u] = (row < M) ? *(const short8v*)&A[(size_t)row * Kp + _kk + c8 + (u&1)*32] : zz; \
    }                                                                                 \
    _Pragma("unroll")                                                                 \
    for (int g = 0; g < 2; ++g)                                                       \
        BR[g] = (bt < T) ? *(const short8v*)&Bsrc[browbase + _kk + c8 + g*32] : zz;   \
} while (0)

    LOAD_AB(ar, br, 0);

    for (int it = 0; it < nk; ++it) {
#pragma unroll
        for (int u = 0; u < 4; ++u)
            *(short8v*)&As[r4 + (u >> 1) * 64][c8 + (u & 1) * 32] = ar[u];
#pragma unroll
        for (int g = 0; g < 2; ++g)
            *(short8v*)&Bs[r4][c8 + g * 32] = br[g];
        __syncthreads();

        if (it + 1 < nk) { LOAD_AB(arn, brn, (it + 1) << 6); }

#pragma unroll
        for (int ks = 0; ks < 2; ++ks) {
            short8v a[4], bb[2];
#pragma unroll
            for (int mi = 0; mi < 4; ++mi)
                a[mi] = *(const short8v*)&As[wm*64 + mi*16 + l15][ks*32 + lg*8];
#pragma unroll
            for (int ni = 0; ni < 2; ++ni)
                bb[ni] = *(const short8v*)&Bs[wn*32 + ni*16 + l15][ks*32 + lg*8];
#pragma unroll
            for (int mi = 0; mi < 4; ++mi)
#pragma unroll
                for (int ni = 0; ni < 2; ++ni)
                    acc[mi][ni] = __builtin_amdgcn_mfma_f32_16x16x32_bf16(
                        a[mi], bb[ni], acc[mi][ni], 0, 0, 0);
        }
        __syncthreads();
#pragma unroll
        for (int u = 0; u < 4; ++u) ar[u] = arn[u];
#pragma unroll
        for (int g = 0; g < 2; ++g) br[g] = brn[g];
    }
#undef LOAD_AB

    // epilogue: C[row=co][col=t]; write [b][t][co]
#pragma unroll
    for (int mi = 0; mi < 4; ++mi) {
#pragma unroll
        for (int ni = 0; ni < 2; ++ni) {
#pragma unroll
            for (int j = 0; j < 4; ++j) {
                int co = m0 + wm*64 + mi*16 + lg*4 + j;
                int t  = t0 + wn*32 + ni*16 + l15;
                if (t >= T) continue;
                if (OUTF32) {
                    if (co < M) {
                        float v = acc[mi][ni][j] + bias[co];
                        if (RELU) v = fmaxf(v, 0.f);
                        ((float*)outv)[((size_t)b * T + t) * M + co] = v;
                    }
                } else {
                    if (co < Mpad) {
                        short o = 0;
                        if (co < M) {
                            float v = acc[mi][ni][j] + bias[co];
                            if (RELU) v = fmaxf(v, 0.f);
                            o = bf16bits(v);
                        }
                        ((short*)outv)[((size_t)b * T + t) * Mpad + co] = o;
                    }
                }
            }
        }
    }
}

// ---------- fused L2-dist attention + log_softmax + log-prior + softmax ----------
// qenc/kenc in [b][t][c] fp32 layout -> float4 staging
__global__ __launch_bounds__(256)
void attn_kernel(const float* __restrict__ qenc, const float* __restrict__ kenc,
                 const float* __restrict__ prior, float* __restrict__ out_attn,
                 float* __restrict__ out_lp)
{
    constexpr int Ca = 80, Ten = 160, Tde = 800, IT = 32, CP = 84;
    __shared__ float ke[Ten][CP];
    __shared__ float qe[IT][CP];
    const int b   = blockIdx.x;
    const int i0  = blockIdx.y * IT;
    const int tid = threadIdx.x;

    for (int l = tid; l < Ten * 20; l += 256) {
        int j = l / 20, q = l - 20 * j;
        *(float4*)&ke[j][q * 4] = *(const float4*)&kenc[((size_t)b * Ten + j) * Ca + q * 4];
    }
    for (int l = tid; l < IT * 20; l += 256) {
        int ii = l / 20, q = l - 20 * ii;
        *(float4*)&qe[ii][q * 4] = *(const float4*)&qenc[((size_t)b * Tde + i0 + ii) * Ca + q * 4];
    }
    __syncthreads();

    const int ii = tid >> 3;
    const int jl = tid & 7;
    const int i  = i0 + ii;

    float s[20];
#pragma unroll
    for (int jj = 0; jj < 20; ++jj) {
        int j = jl + jj * 8;
        float a0 = 0.f, a1 = 0.f, a2 = 0.f, a3 = 0.f;
#pragma unroll
        for (int c = 0; c < Ca; c += 4) {
            float4 qv = *(const float4*)&qe[ii][c];
            float4 kv = *(const float4*)&ke[j][c];
            float d0 = qv.x - kv.x, d1 = qv.y - kv.y;
            float d2 = qv.z - kv.z, d3 = qv.w - kv.w;
            a0 += d0 * d0; a1 += d1 * d1; a2 += d2 * d2; a3 += d3 * d3;
        }
        s[jj] = -TEMP * ((a0 + a1) + (a2 + a3));
    }

    float m = -INFINITY;
#pragma unroll
    for (int jj = 0; jj < 20; ++jj) m = fmaxf(m, s[jj]);
#pragma unroll
    for (int d = 1; d < 8; d <<= 1) m = fmaxf(m, __shfl_xor(m, d));
    float sum = 0.f;
#pragma unroll
    for (int jj = 0; jj < 20; ++jj) sum += expf(s[jj] - m);
#pragma unroll
    for (int d = 1; d < 8; d <<= 1) sum += __shfl_xor(sum, d);
    float lse = logf(sum) + m;

    float lp[20];
    const float* prow = prior + ((size_t)b * Tde + i) * Ten;
#pragma unroll
    for (int jj = 0; jj < 20; ++jj) {
        int j = jl + jj * 8;
        lp[jj] = (s[jj] - lse) + logf(prow[j] + 1e-8f);
    }

    float m2 = -INFINITY;
#pragma unroll
    for (int jj = 0; jj < 20; ++jj) m2 = fmaxf(m2, lp[jj]);
#pragma unroll
    for (int d = 1; d < 8; d <<= 1) m2 = fmaxf(m2, __shfl_xor(m2, d));
    float e[20]; float s2 = 0.f;
#pragma unroll
    for (int jj = 0; jj < 20; ++jj) { e[jj] = expf(lp[jj] - m2); s2 += e[jj]; }
#pragma unroll
    for (int d = 1; d < 8; d <<= 1) s2 += __shfl_xor(s2, d);
    float inv = 1.f / s2;

    float* o0 = out_attn + ((size_t)b * Tde + i) * Ten;
    float* o1 = out_lp   + ((size_t)b * Tde + i) * Ten;
#pragma unroll
    for (int jj = 0; jj < 20; ++jj) {
        int j = jl + jj * 8;
        o0[j] = e[jj] * inv;
        o1[j] = lp[jj];
    }
}

extern "C" void kernel_launch(void* const* d_in, const int* in_sizes, int n_in,
                              void* d_out, int out_size, void* d_ws, size_t ws_size,
                              hipStream_t stream)
{
    const float* queries = (const float*)d_in[0];   // (4,80,800)
    const float* keys    = (const float*)d_in[1];   // (4,512,160)
    const float* prior   = (const float*)d_in[3];   // (4,800,160)
    const float* wk1 = (const float*)d_in[4];
    const float* bk1 = (const float*)d_in[5];
    const float* wk2 = (const float*)d_in[6];
    const float* bk2 = (const float*)d_in[7];
    const float* wq1 = (const float*)d_in[8];
    const float* bq1 = (const float*)d_in[9];
    const float* wq2 = (const float*)d_in[10];
    const float* bq2 = (const float*)d_in[11];
    const float* wq3 = (const float*)d_in[12];
    const float* bq3 = (const float*)d_in[13];

    float* wsp = (float*)d_ws;
    short* wbf = (short*)wsp;
    short* ikeys = wbf + O_IKEYS;
    short* iq    = wbf + O_IQ;
    short* k1T   = wbf + O_K1T;
    short* q1T   = wbf + O_Q1T;   // aliases ikeys (safe: stream-ordered lifetimes)
    short* q2T   = wbf + O_Q2T;   // aliases k1T
    float* kencT = wsp + OF_KENC;
    float* qencT = wsp + OF_QENC;

    float* out0 = (float*)d_out;          // attn (4,1,800,160)
    float* out1 = out0 + 4 * 800 * 160;   // attn_logprob

    // prep: weights->bf16 (padded), im2colT for first-layer inputs
    hipLaunchKernelGGL(cvtw_kernel, dim3((WB_END + 255) / 256), dim3(256), 0, stream,
                       wk1, wk2, wq1, wq2, wq3, wbf);
    hipLaunchKernelGGL(im2col_kernel, dim3(3840 + 3200), dim3(256), 0, stream,
                       keys, queries, ikeys, iq);

    // keys: conv3(512->1024)+relu -> conv1(1024->80)
    hipLaunchKernelGGL((convmm_kernel<true,  false>), dim3(4, 8, 3), dim3(256), 0, stream,
                       ikeys, wbf + WB_K1, bk1, (void*)k1T, 1536, 1024, 1024, 160);
    hipLaunchKernelGGL((convmm_kernel<false, true>),  dim3(4, 1, 3), dim3(256), 0, stream,
                       k1T, wbf + WB_K2, bk2, (void*)kencT, 1024, 80, 80, 160);

    // queries: conv3(80->160)+relu -> conv1(160->80)+relu -> conv1(80->80)
    hipLaunchKernelGGL((convmm_kernel<true,  false>), dim3(4, 2, 13), dim3(256), 0, stream,
                       iq, wbf + WB_Q1, bq1, (void*)q1T, 256, 160, 192, 800);
    hipLaunchKernelGGL((convmm_kernel<true,  false>), dim3(4, 1, 13), dim3(256), 0, stream,
                       q1T, wbf + WB_Q2, bq2, (void*)q2T, 192, 80, 128, 800);
    hipLaunchKernelGGL((convmm_kernel<false, true>),  dim3(4, 1, 13), dim3(256), 0, stream,
                       q2T, wbf + WB_Q3, bq3, (void*)qencT, 128, 80, 80, 800);

    // fused attention
    hipLaunchKernelGGL(attn_kernel, dim3(4, 25), dim3(256), 0, stream,
                       qencT, kencT, prior, out0, out1);
}

// Round 10
// 153.496 us; speedup vs baseline: 2.9108x; 1.3062x over previous
//
#include <hip/hip_runtime.h>
#include <hip/hip_bf16.h>
#include <math.h>

#define TEMP 0.0005f

typedef __attribute__((ext_vector_type(8))) short short8v;
typedef __attribute__((ext_vector_type(4))) float float4v;

__device__ inline short bf16bits(float v) {
    union { float f; unsigned u; } x; x.f = v;
    unsigned r = x.u + 0x7FFFu + ((x.u >> 16) & 1u);   // RNE
    return (short)(r >> 16);
}
__device__ inline float bf2f(short s) {
    union { unsigned u; float f; } x; x.u = ((unsigned)(unsigned short)s) << 16; return x.f;
}

// ============ workspace layout ============
// shorts (from wbf):
#define WB_K1   0          // 1024 x 1536
#define WB_K2   1572864    // 80 x 1024 (tight)
#define WB_Q1   1654784    // 160 x 256 (Ks=240 padded)
#define WB_Q2   1695744    // 80 x 160 (tight)
#define WB_Q3   1708544    // 80 x 80 (tight)
#define WB_END  1714944    // = 256 * 6699 exactly
#define O_IKEYS 1714944    // 640 x 1536 = 983040
#define O_IQ    2697984    // 3200 x 256 = 819200
#define O_K1T   3517184    // 640 x 1024 = 655360
#define O_Q1T   O_IKEYS    // 3200 x 160 = 512000 (alias: ikeys dead after kconv3)
#define SH_END  4172544
// floats (from wsp):
#define OF_KENC (SH_END/2)          // 640*80  = 51200
#define OF_QENC (OF_KENC + 51200)   // 3200*80 = 256000

// ---------- prep: weights->bf16 (+wq1 K-pad) AND im2colT, one dispatch ----------
#define CVTW_BLOCKS 6699
__global__ __launch_bounds__(256)
void prep_kernel(const float* __restrict__ w0, const float* __restrict__ w1,
                 const float* __restrict__ w2, const float* __restrict__ w3,
                 const float* __restrict__ w4,
                 const float* __restrict__ keys, const float* __restrict__ queries,
                 short* __restrict__ wbf, short* __restrict__ ikeys, short* __restrict__ iq)
{
    int bid = blockIdx.x, tid = threadIdx.x;
    if (bid < CVTW_BLOCKS) {
        int i = bid * 256 + tid;               // < WB_END exactly
        float v;
        if      (i < WB_K2) v = w0[i];
        else if (i < WB_Q1) v = w1[i - WB_K2];
        else if (i < WB_Q2) { int rem = i - WB_Q1; int row = rem >> 8, col = rem & 255;
                              v = (col < 240) ? w2[row * 240 + col] : 0.f; }
        else if (i < WB_Q3) v = w3[i - WB_Q2];
        else                v = w4[i - WB_Q3];
        wbf[i] = bf16bits(v);
    } else {
        int b2 = bid - CVTW_BLOCKS;
        if (b2 < 3840) {                       // keys im2colT: 640 rows x 6 chunks
            int row = b2 / 6, chunk = b2 - 6 * (b2 / 6);
            int b = row / 160, t = row - b * 160;
            int k = chunk * 256 + tid;         // < 1536
            int c = k / 3, r = k - 3 * c, ts = t + r - 1;
            float v = (ts >= 0 && ts < 160) ? keys[((size_t)b * 512 + c) * 160 + ts] : 0.f;
            ikeys[(size_t)row * 1536 + k] = bf16bits(v);
        } else {                               // queries im2colT: 3200 rows
            int row = b2 - 3840;
            int b = row / 800, t = row - b * 800;
            int k = tid; short o = 0;
            if (k < 240) {
                int c = k / 3, r = k - 3 * c, ts = t + r - 1;
                if (ts >= 0 && ts < 800) o = bf16bits(queries[((size_t)b * 80 + c) * 800 + ts]);
            }
            iq[(size_t)row * 256 + k] = o;
        }
    }
}

// ---------- keys conv3 as GEMM: M=1024, K=1536, rows=(b,t) 640. BM=BN=64 ----------
__global__ __launch_bounds__(256)
void kconv3_kernel(const short* __restrict__ Bsrc, const short* __restrict__ A,
                   const float* __restrict__ bias, short* __restrict__ out)
{
    const int m0 = blockIdx.x * 64;            // 16 tiles
    const int b  = blockIdx.y / 3, t0 = (blockIdx.y % 3) * 64;  // 12 bt-tiles
    const int tid = threadIdx.x, lane = tid & 63, wid = tid >> 6;
    const int wm = wid >> 1, wn = wid & 1, l15 = lane & 15, lg = lane >> 4;

    __shared__ short As[64][72];
    __shared__ short Bs[64][72];

    float4v acc[2][2];
#pragma unroll
    for (int mi = 0; mi < 2; ++mi)
#pragma unroll
        for (int ni = 0; ni < 2; ++ni) acc[mi][ni] = float4v{0.f,0.f,0.f,0.f};

    const int r4 = tid >> 2, c8 = (tid & 3) * 8;
    const int bt = t0 + r4;
    const short8v zz = {0,0,0,0,0,0,0,0};
    const size_t arow = (size_t)(m0 + r4) * 1536;
    const size_t brow = ((size_t)b * 160 + (bt < 160 ? bt : 0)) * 1536;
    const bool bok = (bt < 160);

    short8v ar[2], br[2], arn[2], brn[2];

#define KLOAD(AR, BR, KK) do { int _k = (KK);                                  \
    _Pragma("unroll") for (int u = 0; u < 2; ++u) {                            \
        AR[u] = *(const short8v*)&A[arow + _k + c8 + u*32];                    \
        BR[u] = bok ? *(const short8v*)&Bsrc[brow + _k + c8 + u*32] : zz;      \
    } } while (0)

    KLOAD(ar, br, 0);
    for (int it = 0; it < 24; ++it) {
#pragma unroll
        for (int u = 0; u < 2; ++u) {
            *(short8v*)&As[r4][c8 + u*32] = ar[u];
            *(short8v*)&Bs[r4][c8 + u*32] = br[u];
        }
        __syncthreads();
        if (it + 1 < 24) { KLOAD(arn, brn, (it + 1) << 6); }
#pragma unroll
        for (int ks = 0; ks < 2; ++ks) {
            short8v a[2], bb[2];
#pragma unroll
            for (int mi = 0; mi < 2; ++mi) a[mi]  = *(const short8v*)&As[wm*32 + mi*16 + l15][ks*32 + lg*8];
#pragma unroll
            for (int ni = 0; ni < 2; ++ni) bb[ni] = *(const short8v*)&Bs[wn*32 + ni*16 + l15][ks*32 + lg*8];
#pragma unroll
            for (int mi = 0; mi < 2; ++mi)
#pragma unroll
                for (int ni = 0; ni < 2; ++ni)
                    acc[mi][ni] = __builtin_amdgcn_mfma_f32_16x16x32_bf16(a[mi], bb[ni], acc[mi][ni], 0,0,0);
        }
        __syncthreads();
#pragma unroll
        for (int u = 0; u < 2; ++u) { ar[u] = arn[u]; br[u] = brn[u]; }
    }
#undef KLOAD

#pragma unroll
    for (int mi = 0; mi < 2; ++mi)
#pragma unroll
        for (int ni = 0; ni < 2; ++ni)
#pragma unroll
            for (int j = 0; j < 4; ++j) {
                int co = m0 + wm*32 + mi*16 + lg*4 + j;
                int t  = t0 + wn*32 + ni*16 + l15;
                if (t < 160)
                    out[((size_t)b*160 + t) * 1024 + co] = bf16bits(fmaxf(acc[mi][ni][j] + bias[co], 0.f));
            }
}

// ---------- q conv3 as GEMM: M=160, Kp=256, rows 3200. BM=BN=64 ----------
__global__ __launch_bounds__(256)
void q1mm_kernel(const short* __restrict__ Bsrc, const short* __restrict__ A,
                 const float* __restrict__ bias, short* __restrict__ out)
{
    const int n0 = blockIdx.x * 64;            // 50 tiles
    const int m0 = blockIdx.y * 64;            // 3 tiles (0,64,128)
    const int tid = threadIdx.x, lane = tid & 63, wid = tid >> 6;
    const int wm = wid >> 1, wn = wid & 1, l15 = lane & 15, lg = lane >> 4;

    __shared__ short As[64][72];
    __shared__ short Bs[64][72];

    float4v acc[2][2];
#pragma unroll
    for (int mi = 0; mi < 2; ++mi)
#pragma unroll
        for (int ni = 0; ni < 2; ++ni) acc[mi][ni] = float4v{0.f,0.f,0.f,0.f};

    const int r4 = tid >> 2, c8 = (tid & 3) * 8;
    const bool aok = (m0 + r4) < 160;
    const short8v zz = {0,0,0,0,0,0,0,0};
    const size_t arow = (size_t)(aok ? (m0 + r4) : 0) * 256;
    const size_t brow = (size_t)(n0 + r4) * 256;

    short8v ar[2], br[2], arn[2], brn[2];

#define QLOAD(AR, BR, KK) do { int _k = (KK);                                  \
    _Pragma("unroll") for (int u = 0; u < 2; ++u) {                            \
        AR[u] = aok ? *(const short8v*)&A[arow + _k + c8 + u*32] : zz;         \
        BR[u] = *(const short8v*)&Bsrc[brow + _k + c8 + u*32];                 \
    } } while (0)

    QLOAD(ar, br, 0);
    for (int it = 0; it < 4; ++it) {
#pragma unroll
        for (int u = 0; u < 2; ++u) {
            *(short8v*)&As[r4][c8 + u*32] = ar[u];
            *(short8v*)&Bs[r4][c8 + u*32] = br[u];
        }
        __syncthreads();
        if (it + 1 < 4) { QLOAD(arn, brn, (it + 1) << 6); }
#pragma unroll
        for (int ks = 0; ks < 2; ++ks) {
            short8v a[2], bb[2];
#pragma unroll
            for (int mi = 0; mi < 2; ++mi) a[mi]  = *(const short8v*)&As[wm*32 + mi*16 + l15][ks*32 + lg*8];
#pragma unroll
            for (int ni = 0; ni < 2; ++ni) bb[ni] = *(const short8v*)&Bs[wn*32 + ni*16 + l15][ks*32 + lg*8];
#pragma unroll
            for (int mi = 0; mi < 2; ++mi)
#pragma unroll
                for (int ni = 0; ni < 2; ++ni)
                    acc[mi][ni] = __builtin_amdgcn_mfma_f32_16x16x32_bf16(a[mi], bb[ni], acc[mi][ni], 0,0,0);
        }
        __syncthreads();
#pragma unroll
        for (int u = 0; u < 2; ++u) { ar[u] = arn[u]; br[u] = brn[u]; }
    }
#undef QLOAD

#pragma unroll
    for (int mi = 0; mi < 2; ++mi)
#pragma unroll
        for (int ni = 0; ni < 2; ++ni)
#pragma unroll
            for (int j = 0; j < 4; ++j) {
                int co  = m0 + wm*32 + mi*16 + lg*4 + j;
                int row = n0 + wn*32 + ni*16 + l15;
                if (co < 160)
                    out[(size_t)row * 160 + co] = bf16bits(fmaxf(acc[mi][ni][j] + bias[co], 0.f));
            }
}

// ---------- mid: kconv1 (1024->80) + q2 (160->80,relu) + q3 (80->80), VALU ----------
// blocks [0,320): kconv1, 2 rows each. blocks [320,1920): qtail, 2 rows each.
__global__ __launch_bounds__(128)
void mid_kernel(const short* __restrict__ k1T, const short* __restrict__ wk2b, const float* __restrict__ bk2,
                float* __restrict__ kenc,
                const short* __restrict__ q1T, const short* __restrict__ wq2b, const float* __restrict__ bq2,
                const short* __restrict__ wq3b, const float* __restrict__ bq3,
                float* __restrict__ qenc)
{
    __shared__ short xrow[2][1024];
    __shared__ float q2row[2][80];
    const int bid = blockIdx.x, tid = threadIdx.x;

    if (bid < 320) {
        const int r0 = bid * 2;
        *(short8v*)&xrow[0][tid * 8] = *(const short8v*)&k1T[(size_t)r0 * 1024 + tid * 8];
        *(short8v*)&xrow[1][tid * 8] = *(const short8v*)&k1T[(size_t)(r0 + 1) * 1024 + tid * 8];
        __syncthreads();
        if (tid < 80) {
            float a0 = 0.f, a1 = 0.f;
            for (int k = 0; k < 1024; k += 8) {
                short8v w  = *(const short8v*)&wk2b[(size_t)tid * 1024 + k];
                short8v x0 = *(const short8v*)&xrow[0][k];
                short8v x1 = *(const short8v*)&xrow[1][k];
#pragma unroll
                for (int e = 0; e < 8; ++e) {
                    float wf = bf2f(w[e]);
                    a0 += wf * bf2f(x0[e]); a1 += wf * bf2f(x1[e]);
                }
            }
            kenc[(size_t)r0 * 80 + tid]       = a0 + bk2[tid];
            kenc[(size_t)(r0 + 1) * 80 + tid] = a1 + bk2[tid];
        }
    } else {
        const int r0 = (bid - 320) * 2;
        if (tid < 40) {
            int which = tid / 20, part = tid - 20 * (tid / 20);
            *(short8v*)&xrow[which][part * 8] = *(const short8v*)&q1T[(size_t)(r0 + which) * 160 + part * 8];
        }
        __syncthreads();
        if (tid < 80) {
            float a0 = 0.f, a1 = 0.f;
            for (int k = 0; k < 160; k += 8) {
                short8v w  = *(const short8v*)&wq2b[(size_t)tid * 160 + k];
                short8v x0 = *(const short8v*)&xrow[0][k];
                short8v x1 = *(const short8v*)&xrow[1][k];
#pragma unroll
                for (int e = 0; e < 8; ++e) {
                    float wf = bf2f(w[e]);
                    a0 += wf * bf2f(x0[e]); a1 += wf * bf2f(x1[e]);
                }
            }
            q2row[0][tid] = fmaxf(a0 + bq2[tid], 0.f);
            q2row[1][tid] = fmaxf(a1 + bq2[tid], 0.f);
        }
        __syncthreads();
        if (tid < 80) {
            float a0 = 0.f, a1 = 0.f;
            for (int k = 0; k < 80; ++k) {
                float wf = bf2f(wq3b[tid * 80 + k]);
                a0 += wf * q2row[0][k]; a1 += wf * q2row[1][k];
            }
            qenc[(size_t)r0 * 80 + tid]       = a0 + bq3[tid];
            qenc[(size_t)(r0 + 1) * 80 + tid] = a1 + bq3[tid];
        }
    }
}

// ---------- fused attention, IT=16 -> 200 blocks ----------
__global__ __launch_bounds__(256)
void attn_kernel(const float* __restrict__ qenc, const float* __restrict__ kenc,
                 const float* __restrict__ prior, float* __restrict__ out_attn,
                 float* __restrict__ out_lp)
{
    constexpr int Ca = 80, Ten = 160, Tde = 800, IT = 16, CP = 84;
    __shared__ float ke[Ten][CP];
    __shared__ float qe[IT][CP];
    const int b  = blockIdx.x;
    const int i0 = blockIdx.y * IT;
    const int tid = threadIdx.x;

    for (int l = tid; l < Ten * 20; l += 256) {
        int j = l / 20, q = l - 20 * j;
        *(float4*)&ke[j][q * 4] = *(const float4*)&kenc[((size_t)b * Ten + j) * Ca + q * 4];
    }
    for (int l = tid; l < IT * 20; l += 256) {
        int ii = l / 20, q = l - 20 * ii;
        *(float4*)&qe[ii][q * 4] = *(const float4*)&qenc[((size_t)b * Tde + i0 + ii) * Ca + q * 4];
    }
    __syncthreads();

    const int ii = tid >> 4;       // 0..15
    const int jl = tid & 15;       // 0..15
    const int i  = i0 + ii;

    float s[10];
#pragma unroll
    for (int jj = 0; jj < 10; ++jj) {
        int j = jl + jj * 16;
        float a0 = 0.f, a1 = 0.f, a2 = 0.f, a3 = 0.f;
#pragma unroll
        for (int c = 0; c < Ca; c += 4) {
            float4 qv = *(const float4*)&qe[ii][c];
            float4 kv = *(const float4*)&ke[j][c];
            float d0 = qv.x - kv.x, d1 = qv.y - kv.y;
            float d2 = qv.z - kv.z, d3 = qv.w - kv.w;
            a0 += d0 * d0; a1 += d1 * d1; a2 += d2 * d2; a3 += d3 * d3;
        }
        s[jj] = -TEMP * ((a0 + a1) + (a2 + a3));
    }

    float m = -INFINITY;
#pragma unroll
    for (int jj = 0; jj < 10; ++jj) m = fmaxf(m, s[jj]);
#pragma unroll
    for (int d = 1; d < 16; d <<= 1) m = fmaxf(m, __shfl_xor(m, d));
    float sum = 0.f;
#pragma unroll
    for (int jj = 0; jj < 10; ++jj) sum += expf(s[jj] - m);
#pragma unroll
    for (int d = 1; d < 16; d <<= 1) sum += __shfl_xor(sum, d);
    float lse = logf(sum) + m;

    float lp[10];
    const float* prow = prior + ((size_t)b * Tde + i) * Ten;
#pragma unroll
    for (int jj = 0; jj < 10; ++jj) {
        int j = jl + jj * 16;
        lp[jj] = (s[jj] - lse) + logf(prow[j] + 1e-8f);
    }

    float m2 = -INFINITY;
#pragma unroll
    for (int jj = 0; jj < 10; ++jj) m2 = fmaxf(m2, lp[jj]);
#pragma unroll
    for (int d = 1; d < 16; d <<= 1) m2 = fmaxf(m2, __shfl_xor(m2, d));
    float e[10]; float s2 = 0.f;
#pragma unroll
    for (int jj = 0; jj < 10; ++jj) { e[jj] = expf(lp[jj] - m2); s2 += e[jj]; }
#pragma unroll
    for (int d = 1; d < 16; d <<= 1) s2 += __shfl_xor(s2, d);
    float inv = 1.f / s2;

    float* o0 = out_attn + ((size_t)b * Tde + i) * Ten;
    float* o1 = out_lp   + ((size_t)b * Tde + i) * Ten;
#pragma unroll
    for (int jj = 0; jj < 10; ++jj) {
        int j = jl + jj * 16;
        o0[j] = e[jj] * inv;
        o1[j] = lp[jj];
    }
}

extern "C" void kernel_launch(void* const* d_in, const int* in_sizes, int n_in,
                              void* d_out, int out_size, void* d_ws, size_t ws_size,
                              hipStream_t stream)
{
    const float* queries = (const float*)d_in[0];
    const float* keys    = (const float*)d_in[1];
    const float* prior   = (const float*)d_in[3];
    const float* wk1 = (const float*)d_in[4];
    const float* bk1 = (const float*)d_in[5];
    const float* wk2 = (const float*)d_in[6];
    const float* bk2 = (const float*)d_in[7];
    const float* wq1 = (const float*)d_in[8];
    const float* bq1 = (const float*)d_in[9];
    const float* wq2 = (const float*)d_in[10];
    const float* bq2 = (const float*)d_in[11];
    const float* wq3 = (const float*)d_in[12];
    const float* bq3 = (const float*)d_in[13];

    float* wsp = (float*)d_ws;
    short* wbf = (short*)wsp;
    short* ikeys = wbf + O_IKEYS;
    short* iq    = wbf + O_IQ;
    short* k1T   = wbf + O_K1T;
    short* q1T   = wbf + O_Q1T;      // aliases ikeys (dead after kconv3)
    float* kencT = wsp + OF_KENC;
    float* qencT = wsp + OF_QENC;

    float* out0 = (float*)d_out;
    float* out1 = out0 + 4 * 800 * 160;

    hipLaunchKernelGGL(prep_kernel, dim3(CVTW_BLOCKS + 3840 + 3200), dim3(256), 0, stream,
                       wk1, wk2, wq1, wq2, wq3, keys, queries, wbf, ikeys, iq);

    hipLaunchKernelGGL(kconv3_kernel, dim3(16, 12), dim3(256), 0, stream,
                       ikeys, wbf + WB_K1, bk1, k1T);

    hipLaunchKernelGGL(q1mm_kernel, dim3(50, 3), dim3(256), 0, stream,
                       iq, wbf + WB_Q1, bq1, q1T);

    hipLaunchKernelGGL(mid_kernel, dim3(1920), dim3(128), 0, stream,
                       k1T, wbf + WB_K2, bk2, kencT,
                       q1T, wbf + WB_Q2, bq2, wbf + WB_Q3, bq3, qencT);

    hipLaunchKernelGGL(attn_kernel, dim3(4, 50), dim3(256), 0, stream,
                       qencT, kencT, prior, out0, out1);
}

// Round 13
// 147.398 us; speedup vs baseline: 3.0312x; 1.0414x over previous
//
#include <hip/hip_runtime.h>
#include <hip/hip_bf16.h>
#include <math.h>

#define TEMP 0.0005f

typedef __attribute__((ext_vector_type(8))) short short8v;
typedef __attribute__((ext_vector_type(4))) float float4v;

__device__ inline short bf16bits(float v) {
    union { float f; unsigned u; } x; x.f = v;
    unsigned r = x.u + 0x7FFFu + ((x.u >> 16) & 1u);   // RNE
    return (short)(r >> 16);
}
__device__ inline float bf2f(short s) {
    union { unsigned u; float f; } x; x.u = ((unsigned)(unsigned short)s) << 16; return x.f;
}

// ============ workspace layout ============
// shorts (from wbf):
#define WB_K1   0          // 1024 x 1536
#define WB_K2   1572864    // 80 x 1024 (tight)
#define WB_Q1   1654784    // 160 x 256 (Ks=240 padded)
#define WB_Q2   1695744    // 80 x 160 (tight)
#define WB_Q3   1708544    // 80 x 80 (tight)
#define WB_END  1714944    // = 256 * 6699 exactly
#define O_IKEYS 1714944    // 640 x 1536 = 983040
#define O_IQ    2697984    // 3200 x 256 = 819200
#define O_K1T   3517184    // 640 x 1024 = 655360
#define O_Q1T   O_IKEYS    // 3200 x 160 = 512000 (alias: ikeys dead after gemm)
#define SH_END  4172544
// floats (from wsp):
#define OF_KENC (SH_END/2)          // 640*80 = 51200

// ---------- prep: weights->bf16 (+pads) AND im2colT, one dispatch ----------
#define CVTW_BLOCKS 6699
__global__ __launch_bounds__(256)
void prep_kernel(const float* __restrict__ w0, const float* __restrict__ w1,
                 const float* __restrict__ w2, const float* __restrict__ w3,
                 const float* __restrict__ w4,
                 const float* __restrict__ keys, const float* __restrict__ queries,
                 short* __restrict__ wbf, short* __restrict__ ikeys, short* __restrict__ iq)
{
    int bid = blockIdx.x, tid = threadIdx.x;
    if (bid < CVTW_BLOCKS) {
        int i = bid * 256 + tid;               // < WB_END exactly
        float v;
        if      (i < WB_K2) v = w0[i];
        else if (i < WB_Q1) v = w1[i - WB_K2];
        else if (i < WB_Q2) { int rem = i - WB_Q1; int row = rem >> 8, col = rem & 255;
                              v = (col < 240) ? w2[row * 240 + col] : 0.f; }
        else if (i < WB_Q3) v = w3[i - WB_Q2];
        else                v = w4[i - WB_Q3];
        wbf[i] = bf16bits(v);
    } else {
        int b2 = bid - CVTW_BLOCKS;
        if (b2 < 3840) {                       // keys im2colT: 640 rows x 6 chunks
            int row = b2 / 6, chunk = b2 - 6 * (b2 / 6);
            int b = row / 160, t = row - b * 160;
            int k = chunk * 256 + tid;         // < 1536
            int c = k / 3, r = k - 3 * c, ts = t + r - 1;
            float v = (ts >= 0 && ts < 160) ? keys[((size_t)b * 512 + c) * 160 + ts] : 0.f;
            ikeys[(size_t)row * 1536 + k] = bf16bits(v);
        } else {                               // queries im2colT: 3200 rows
            int row = b2 - 3840;
            int b = row / 800, t = row - b * 800;
            int k = tid; short o = 0;
            if (k < 240) {
                int c = k / 3, r = k - 3 * c, ts = t + r - 1;
                if (ts >= 0 && ts < 800) o = bf16bits(queries[((size_t)b * 80 + c) * 800 + ts]);
            }
            iq[(size_t)row * 256 + k] = o;
        }
    }
}

// ---------- fused GEMM dispatch: kconv3 (192 blocks) + q1 conv (150 blocks) ----------
__global__ __launch_bounds__(256)
void gemm_kernel(const short* __restrict__ ikeys, const short* __restrict__ wk1b,
                 const float* __restrict__ bk1, short* __restrict__ k1T,
                 const short* __restrict__ iq, const short* __restrict__ wq1b,
                 const float* __restrict__ bq1, short* __restrict__ q1T)
{
    const int bid = blockIdx.x;
    const int tid = threadIdx.x, lane = tid & 63, wid = tid >> 6;
    const int wm = wid >> 1, wn = wid & 1, l15 = lane & 15, lg = lane >> 4;
    const int r4 = tid >> 2, c8 = (tid & 3) * 8;
    const short8v zz = {0,0,0,0,0,0,0,0};

    __shared__ short As[64][72];
    __shared__ short Bs[64][72];

    float4v acc[2][2];
#pragma unroll
    for (int mi = 0; mi < 2; ++mi)
#pragma unroll
        for (int ni = 0; ni < 2; ++ni) acc[mi][ni] = float4v{0.f,0.f,0.f,0.f};

    if (bid < 192) {
        // ---- keys conv3: M=1024, K=1536, rows 640 ----
        const int m0 = (bid & 15) * 64;
        const int by = bid >> 4;               // 0..11
        const int b = by / 3, t0 = (by % 3) * 64;
        const int bt = t0 + r4;
        const bool bok = (bt < 160);
        const size_t arow = (size_t)(m0 + r4) * 1536;
        const size_t brow = ((size_t)b * 160 + (bok ? bt : 0)) * 1536;

        short8v ar[2], br[2], arn[2], brn[2];
#define KLOAD(AR, BR, KK) do { int _k = (KK);                               \
        _Pragma("unroll") for (int u = 0; u < 2; ++u) {                     \
            AR[u] = *(const short8v*)&wk1b[arow + _k + c8 + u*32];          \
            BR[u] = bok ? *(const short8v*)&ikeys[brow + _k + c8 + u*32] : zz; \
        } } while (0)
        KLOAD(ar, br, 0);
        for (int it = 0; it < 24; ++it) {
#pragma unroll
            for (int u = 0; u < 2; ++u) {
                *(short8v*)&As[r4][c8 + u*32] = ar[u];
                *(short8v*)&Bs[r4][c8 + u*32] = br[u];
            }
            __syncthreads();
            if (it + 1 < 24) { KLOAD(arn, brn, (it + 1) << 6); }
#pragma unroll
            for (int ks = 0; ks < 2; ++ks) {
                short8v a[2], bb[2];
#pragma unroll
                for (int mi = 0; mi < 2; ++mi) a[mi]  = *(const short8v*)&As[wm*32 + mi*16 + l15][ks*32 + lg*8];
#pragma unroll
                for (int ni = 0; ni < 2; ++ni) bb[ni] = *(const short8v*)&Bs[wn*32 + ni*16 + l15][ks*32 + lg*8];
#pragma unroll
                for (int mi = 0; mi < 2; ++mi)
#pragma unroll
                    for (int ni = 0; ni < 2; ++ni)
                        acc[mi][ni] = __builtin_amdgcn_mfma_f32_16x16x32_bf16(a[mi], bb[ni], acc[mi][ni], 0,0,0);
            }
            __syncthreads();
#pragma unroll
            for (int u = 0; u < 2; ++u) { ar[u] = arn[u]; br[u] = brn[u]; }
        }
#undef KLOAD
#pragma unroll
        for (int mi = 0; mi < 2; ++mi)
#pragma unroll
            for (int ni = 0; ni < 2; ++ni)
#pragma unroll
                for (int j = 0; j < 4; ++j) {
                    int co = m0 + wm*32 + mi*16 + lg*4 + j;
                    int t  = t0 + wn*32 + ni*16 + l15;
                    if (t < 160)
                        k1T[((size_t)b*160 + t) * 1024 + co] = bf16bits(fmaxf(acc[mi][ni][j] + bk1[co], 0.f));
                }
    } else {
        // ---- queries conv3: M=160, Kp=256, rows 3200 ----
        const int b2 = bid - 192;
        const int n0 = (b2 % 50) * 64;
        const int m0 = (b2 / 50) * 64;
        const bool aok = (m0 + r4) < 160;
        const size_t arow = (size_t)(aok ? (m0 + r4) : 0) * 256;
        const size_t brow = (size_t)(n0 + r4) * 256;

        short8v ar[2], br[2], arn[2], brn[2];
#define QLOAD(AR, BR, KK) do { int _k = (KK);                               \
        _Pragma("unroll") for (int u = 0; u < 2; ++u) {                     \
            AR[u] = aok ? *(const short8v*)&wq1b[arow + _k + c8 + u*32] : zz; \
            BR[u] = *(const short8v*)&iq[brow + _k + c8 + u*32];            \
        } } while (0)
        QLOAD(ar, br, 0);
        for (int it = 0; it < 4; ++it) {
#pragma unroll
            for (int u = 0; u < 2; ++u) {
                *(short8v*)&As[r4][c8 + u*32] = ar[u];
                *(short8v*)&Bs[r4][c8 + u*32] = br[u];
            }
            __syncthreads();
            if (it + 1 < 4) { QLOAD(arn, brn, (it + 1) << 6); }
#pragma unroll
            for (int ks = 0; ks < 2; ++ks) {
                short8v a[2], bb[2];
#pragma unroll
                for (int mi = 0; mi < 2; ++mi) a[mi]  = *(const short8v*)&As[wm*32 + mi*16 + l15][ks*32 + lg*8];
#pragma unroll
                for (int ni = 0; ni < 2; ++ni) bb[ni] = *(const short8v*)&Bs[wn*32 + ni*16 + l15][ks*32 + lg*8];
#pragma unroll
                for (int mi = 0; mi < 2; ++mi)
#pragma unroll
                    for (int ni = 0; ni < 2; ++ni)
                        acc[mi][ni] = __builtin_amdgcn_mfma_f32_16x16x32_bf16(a[mi], bb[ni], acc[mi][ni], 0,0,0);
            }
            __syncthreads();
#pragma unroll
            for (int u = 0; u < 2; ++u) { ar[u] = arn[u]; br[u] = brn[u]; }
        }
#undef QLOAD
#pragma unroll
        for (int mi = 0; mi < 2; ++mi)
#pragma unroll
            for (int ni = 0; ni < 2; ++ni)
#pragma unroll
                for (int j = 0; j < 4; ++j) {
                    int co  = m0 + wm*32 + mi*16 + lg*4 + j;
                    int row = n0 + wn*32 + ni*16 + l15;
                    if (co < 160)
                        q1T[(size_t)row * 160 + co] = bf16bits(fmaxf(acc[mi][ni][j] + bq1[co], 0.f));
                }
    }
}

// ---------- kconv1 as MFMA GEMM: M=bt rows (640), N=80 couts, K=1024 ----------
// 10 blocks x 64 rows; 4 waves, each 16 rows x 80 couts (5 n-frags)
__global__ __launch_bounds__(256)
void kconv1_kernel(const short* __restrict__ k1T, const short* __restrict__ wk2b,
                   const float* __restrict__ bk2, float* __restrict__ kenc)
{
    const int r0 = blockIdx.x * 64;
    const int tid = threadIdx.x, lane = tid & 63, w = tid >> 6;
    const int l15 = lane & 15, lg = lane >> 4;

    __shared__ short As[64][72];   // X rows
    __shared__ short Bs[96][72];   // W rows (80 used, staged 96 for even loads)

    float4v acc[5];
#pragma unroll
    for (int nf = 0; nf < 5; ++nf) acc[nf] = float4v{0.f,0.f,0.f,0.f};

    short8v ar[2], br[3], arn[2], brn[3];
#define CLOAD(AR, BR, KK) do { int _k = (KK);                                  \
    _Pragma("unroll") for (int u = 0; u < 2; ++u) {                            \
        int l = tid + 256*u; int rr = l >> 3, cc = (l & 7) * 8;                \
        AR[u] = *(const short8v*)&k1T[(size_t)(r0 + rr) * 1024 + _k + cc];     \
    }                                                                          \
    _Pragma("unroll") for (int u = 0; u < 3; ++u) {                            \
        int l = tid + 256*u; int rr = l >> 3, cc = (l & 7) * 8;                \
        int wr = (rr < 80) ? rr : rr - 80;                                     \
        BR[u] = *(const short8v*)&wk2b[(size_t)wr * 1024 + _k + cc];           \
    } } while (0)

    CLOAD(ar, br, 0);
    for (int it = 0; it < 16; ++it) {
#pragma unroll
        for (int u = 0; u < 2; ++u) {
            int l = tid + 256*u; int rr = l >> 3, cc = (l & 7) * 8;
            *(short8v*)&As[rr][cc] = ar[u];
        }
#pragma unroll
        for (int u = 0; u < 3; ++u) {
            int l = tid + 256*u; int rr = l >> 3, cc = (l & 7) * 8;
            *(short8v*)&Bs[rr][cc] = br[u];
        }
        __syncthreads();
        if (it + 1 < 16) { CLOAD(arn, brn, (it + 1) << 6); }
#pragma unroll
        for (int ks = 0; ks < 2; ++ks) {
            short8v a = *(const short8v*)&As[w*16 + l15][ks*32 + lg*8];
#pragma unroll
            for (int nf = 0; nf < 5; ++nf) {
                short8v bb = *(const short8v*)&Bs[nf*16 + l15][ks*32 + lg*8];
                acc[nf] = __builtin_amdgcn_mfma_f32_16x16x32_bf16(a, bb, acc[nf], 0,0,0);
            }
        }
        __syncthreads();
#pragma unroll
        for (int u = 0; u < 2; ++u) ar[u] = arn[u];
#pragma unroll
        for (int u = 0; u < 3; ++u) br[u] = brn[u];
    }
#undef CLOAD

#pragma unroll
    for (int nf = 0; nf < 5; ++nf)
#pragma unroll
        for (int j = 0; j < 4; ++j) {
            int row = r0 + w*16 + lg*4 + j;      // bt row
            int co  = nf*16 + l15;
            kenc[(size_t)row * 80 + co] = acc[nf][j] + bk2[co];
        }
}

// ---------- attn: fused q2+q3 + L2-dist + log_softmax + prior + softmax ----------
__global__ __launch_bounds__(256)
void attn_kernel(const short* __restrict__ q1T, const short* __restrict__ wq2b,
                 const float* __restrict__ bq2, const short* __restrict__ wq3b,
                 const float* __restrict__ bq3,
                 const float* __restrict__ kenc, const float* __restrict__ prior,
                 float* __restrict__ out_attn, float* __restrict__ out_lp)
{
    constexpr int Ca = 80, Ten = 160, Tde = 800, IT = 16, CP = 84;
    __shared__ float ke[Ten][CP];
    __shared__ short q1s[IT][168];
    __shared__ float q2s[IT][CP];
    __shared__ float qe[IT][CP];
    const int b  = blockIdx.x;
    const int i0 = blockIdx.y * IT;
    const int tid = threadIdx.x;

    // stage kenc (f32 [b*160+j][80]) and q1T rows (bf16 [b*800+i][160])
    for (int l = tid; l < Ten * 20; l += 256) {
        int j = l / 20, q = l - 20 * j;
        *(float4*)&ke[j][q * 4] = *(const float4*)&kenc[((size_t)b * Ten + j) * Ca + q * 4];
    }
    for (int l = tid; l < IT * 20; l += 256) {
        int row = l / 20, part = l - 20 * row;
        *(short8v*)&q1s[row][part * 8] = *(const short8v*)&q1T[((size_t)b * Tde + i0 + row) * 160 + part * 8];
    }
    __syncthreads();

    // q2 = relu(W2 q1 + b2): 16x80 outputs, 5 per thread
#pragma unroll
    for (int p = 0; p < 5; ++p) {
        int o = p * 256 + tid;       // < 1280
        int row = o / 80, co = o - 80 * row;
        float a = 0.f;
        for (int k = 0; k < 160; k += 8) {
            short8v wv = *(const short8v*)&wq2b[(size_t)co * 160 + k];
            short8v xv = *(const short8v*)&q1s[row][k];
#pragma unroll
            for (int e = 0; e < 8; ++e) a += bf2f(wv[e]) * bf2f(xv[e]);
        }
        q2s[row][co] = fmaxf(a + bq2[co], 0.f);
    }
    __syncthreads();

    // qe = W3 q2 + b3
#pragma unroll
    for (int p = 0; p < 5; ++p) {
        int o = p * 256 + tid;
        int row = o / 80, co = o - 80 * row;
        float a = 0.f;
        for (int k = 0; k < 80; k += 8) {
            short8v wv = *(const short8v*)&wq3b[(size_t)co * 80 + k];
#pragma unroll
            for (int e = 0; e < 8; ++e) a += bf2f(wv[e]) * q2s[row][k + e];
        }
        qe[row][co] = a + bq3[co];
    }
    __syncthreads();

    const int ii = tid >> 4;       // 0..15
    const int jl = tid & 15;       // 0..15
    const int i  = i0 + ii;

    float s[10];
#pragma unroll
    for (int jj = 0; jj < 10; ++jj) {
        int j = jl + jj * 16;
        float a0 = 0.f, a1 = 0.f, a2 = 0.f, a3 = 0.f;
#pragma unroll
        for (int c = 0; c < Ca; c += 4) {
            float4 qv = *(const float4*)&qe[ii][c];
            float4 kv = *(const float4*)&ke[j][c];
            float d0 = qv.x - kv.x, d1 = qv.y - kv.y;
            float d2 = qv.z - kv.z, d3 = qv.w - kv.w;
            a0 += d0 * d0; a1 += d1 * d1; a2 += d2 * d2; a3 += d3 * d3;
        }
        s[jj] = -TEMP * ((a0 + a1) + (a2 + a3));
    }

    float m = -INFINITY;
#pragma unroll
    for (int jj = 0; jj < 10; ++jj) m = fmaxf(m, s[jj]);
#pragma unroll
    for (int d = 1; d < 16; d <<= 1) m = fmaxf(m, __shfl_xor(m, d));
    float sum = 0.f;
#pragma unroll
    for (int jj = 0; jj < 10; ++jj) sum += expf(s[jj] - m);
#pragma unroll
    for (int d = 1; d < 16; d <<= 1) sum += __shfl_xor(sum, d);
    float lse = logf(sum) + m;

    float lp[10];
    const float* prow = prior + ((size_t)b * Tde + i) * Ten;
#pragma unroll
    for (int jj = 0; jj < 10; ++jj) {
        int j = jl + jj * 16;
        lp[jj] = (s[jj] - lse) + logf(prow[j] + 1e-8f);
    }

    float m2 = -INFINITY;
#pragma unroll
    for (int jj = 0; jj < 10; ++jj) m2 = fmaxf(m2, lp[jj]);
#pragma unroll
    for (int d = 1; d < 16; d <<= 1) m2 = fmaxf(m2, __shfl_xor(m2, d));
    float e[10]; float s2 = 0.f;
#pragma unroll
    for (int jj = 0; jj < 10; ++jj) { e[jj] = expf(lp[jj] - m2); s2 += e[jj]; }
#pragma unroll
    for (int d = 1; d < 16; d <<= 1) s2 += __shfl_xor(s2, d);
    float inv = 1.f / s2;

    float* o0 = out_attn + ((size_t)b * Tde + i) * Ten;
    float* o1 = out_lp   + ((size_t)b * Tde + i) * Ten;
#pragma unroll
    for (int jj = 0; jj < 10; ++jj) {
        int j = jl + jj * 16;
        o0[j] = e[jj] * inv;
        o1[j] = lp[jj];
    }
}

extern "C" void kernel_launch(void* const* d_in, const int* in_sizes, int n_in,
                              void* d_out, int out_size, void* d_ws, size_t ws_size,
                              hipStream_t stream)
{
    const float* queries = (const float*)d_in[0];
    const float* keys    = (const float*)d_in[1];
    const float* prior   = (const float*)d_in[3];
    const float* wk1 = (const float*)d_in[4];
    const float* bk1 = (const float*)d_in[5];
    const float* wk2 = (const float*)d_in[6];
    const float* bk2 = (const float*)d_in[7];
    const float* wq1 = (const float*)d_in[8];
    const float* bq1 = (const float*)d_in[9];
    const float* wq2 = (const float*)d_in[10];
    const float* bq2 = (const float*)d_in[11];
    const float* wq3 = (const float*)d_in[12];
    const float* bq3 = (const float*)d_in[13];

    float* wsp = (float*)d_ws;
    short* wbf = (short*)wsp;
    short* ikeys = wbf + O_IKEYS;
    short* iq    = wbf + O_IQ;
    short* k1T   = wbf + O_K1T;
    short* q1T   = wbf + O_Q1T;      // aliases ikeys (dead after gemm_kernel)
    float* kencT = wsp + OF_KENC;

    float* out0 = (float*)d_out;
    float* out1 = out0 + 4 * 800 * 160;

    hipLaunchKernelGGL(prep_kernel, dim3(CVTW_BLOCKS + 3840 + 3200), dim3(256), 0, stream,
                       wk1, wk2, wq1, wq2, wq3, keys, queries, wbf, ikeys, iq);

    hipLaunchKernelGGL(gemm_kernel, dim3(342), dim3(256), 0, stream,
                       ikeys, wbf + WB_K1, bk1, k1T,
                       iq, wbf + WB_Q1, bq1, q1T);

    hipLaunchKernelGGL(kconv1_kernel, dim3(10), dim3(256), 0, stream,
                       k1T, wbf + WB_K2, bk2, kencT);

    hipLaunchKernelGGL(attn_kernel, dim3(4, 50), dim3(256), 0, stream,
                       q1T, wbf + WB_Q2, bq2, wbf + WB_Q3, bq3,
                       kencT, prior, out0, out1);
}